// Round 19
// baseline (1429.803 us; speedup 1.0000x reference)
//
#include <hip/hip_runtime.h>
#include <hip/hip_bf16.h>
#include <cstdint>

#define LNUM 6
#define BNUM 4
#define TSEQ 1024
#define DMOD 512
#define HNUM 8
#define FDIM 2048
#define DHEAD 64
#define NEVENTS 65536
#define EPS_LN 1e-3f
#define ATT_SCALE 0.125f

#define GF_ACC 1
#define GF_RELU 2
#define GF_BIAS 4
#define GF_SPLIT 8
#define GF_QKV 16
#define GF_PART 32

typedef float f32x4 __attribute__((ext_vector_type(4)));
typedef short bf16x8 __attribute__((ext_vector_type(8)));
typedef unsigned short u16;
typedef unsigned int u32;

__device__ inline u16 f2bf(float f){
  u32 u = __builtin_bit_cast(u32, f);
  u32 r = (u + 0x7fffu + ((u >> 16) & 1u)) >> 16;
  return (u16)r;
}
__device__ inline float bf2f(u16 u){
  return __builtin_bit_cast(float, (u32)u << 16);
}
__device__ inline void split2(float x, u16 &hi, u16 &lo){
  u16 h = f2bf(x);
  lo = f2bf(x - bf2f(h));
  hi = h;
}
__device__ inline void gload16(const void* g, void* l){
  __builtin_amdgcn_global_load_lds(
      (const __attribute__((address_space(1))) void*)g,
      (__attribute__((address_space(3))) void*)l, 16, 0, 0);
}

// ------- LayerNorm (+fused split-K reduce + optional col-bias + residual) -------
__global__ __launch_bounds__(256) void ln_kernel(float* __restrict__ x,
    const float* __restrict__ part, const float* __restrict__ abias,
    const float* __restrict__ s, const float* __restrict__ bsh,
    float* __restrict__ yf, u16* __restrict__ yh, u16* __restrict__ yl, int mode){
  int row = blockIdx.x, tid = threadIdx.x;
  float* xr = x + (size_t)row * DMOD;
  float2 v = *reinterpret_cast<const float2*>(xr + tid*2);
  if (part){
    const size_t MN = (size_t)BNUM*TSEQ*DMOD;
    const size_t o = (size_t)row*DMOD + tid*2;
    float2 p0 = *reinterpret_cast<const float2*>(part + o);
    float2 p1 = *reinterpret_cast<const float2*>(part + MN + o);
    v.x += p0.x + p1.x; v.y += p0.y + p1.y;
    if (abias){
      v.x += abias[tid*2]; v.y += abias[tid*2+1];
    }
    *reinterpret_cast<float2*>(xr + tid*2) = v;   // materialize residual
  }
  float sum = v.x + v.y, sq = v.x*v.x + v.y*v.y;
  #pragma unroll
  for (int off = 32; off > 0; off >>= 1){
    sum += __shfl_down(sum, off);
    sq  += __shfl_down(sq, off);
  }
  __shared__ float ss[4], sq2[4];
  int wid = tid >> 6;
  if ((tid & 63) == 0){ ss[wid] = sum; sq2[wid] = sq; }
  __syncthreads();
  sum = ss[0]+ss[1]+ss[2]+ss[3];
  sq  = sq2[0]+sq2[1]+sq2[2]+sq2[3];
  float mean = sum * (1.f/DMOD);
  float var  = sq * (1.f/DMOD) - mean*mean;
  float rstd = rsqrtf(var + EPS_LN);
  float2 sc = *reinterpret_cast<const float2*>(s + tid*2);
  float2 bi = *reinterpret_cast<const float2*>(bsh + tid*2);
  float ox = (v.x - mean)*rstd*sc.x + bi.x;
  float oy = (v.y - mean)*rstd*sc.y + bi.y;
  if (mode == 0){
    u16 h0,l0,h1,l1;
    split2(ox,h0,l0); split2(oy,h1,l1);
    *(u32*)(yh + (size_t)row*DMOD + tid*2) = (u32)h0 | ((u32)h1<<16);
    *(u32*)(yl + (size_t)row*DMOD + tid*2) = (u32)l0 | ((u32)l1<<16);
  } else {
    float2 o; o.x = ox; o.y = oy;
    *reinterpret_cast<float2*>(yf + (size_t)row*DMOD + tid*2) = o;
  }
}

// --------- fused weight transpose+split for Wq,Wk,Wv,Wo,W1,W2 (768 blocks) -----
__global__ __launch_bounds__(256) void wsplit6(
    const float* __restrict__ Wq, const float* __restrict__ Wk,
    const float* __restrict__ Wv, const float* __restrict__ Wo,
    const float* __restrict__ W1, const float* __restrict__ W2, int l,
    u16* __restrict__ wqkvh, u16* __restrict__ wqkvl,
    u16* __restrict__ woh,   u16* __restrict__ wol,
    u16* __restrict__ w1h,   u16* __restrict__ w1l,
    u16* __restrict__ w2h,   u16* __restrict__ w2l){
  __shared__ float T[64][65];
  int id = blockIdx.x;
  const float* src; u16 *dh, *dl; int N, Kst, bx, by;
  if (id < 256){
    const int which = id >> 6, sub = id & 63;
    bx = sub & 7; by = sub >> 3; N = 512; Kst = 512;
    if (which == 0){ src = Wq; dh = wqkvh;            dl = wqkvl; }
    else if (which == 1){ src = Wk; dh = wqkvh + 512*512; dl = wqkvl + 512*512; }
    else if (which == 2){ src = Wv; dh = wqkvh + 2*512*512; dl = wqkvl + 2*512*512; }
    else { src = Wo; dh = woh; dl = wol; }
    src += (size_t)l*DMOD*DMOD;
  } else if (id < 512){
    int sub = id - 256;
    bx = sub & 31; by = sub >> 5; N = 2048; Kst = 512;
    src = W1 + (size_t)l*DMOD*FDIM; dh = w1h; dl = w1l;
  } else {
    int sub = id - 512;
    bx = sub & 7; by = sub >> 3; N = 512; Kst = 2048;   // by 0..31 (K=2048 rows)
    src = W2 + (size_t)l*FDIM*DMOD; dh = w2h; dl = w2l;
  }
  const int k0 = by*64, n0 = bx*64;
  const int tid = threadIdx.x;
  {
    const int r = tid>>2, cseg = (tid&3)*16;
    const float* sp = src + (size_t)(k0+r)*N + n0 + cseg;
    #pragma unroll
    for (int i = 0; i < 16; i += 4){
      float4 v = *(const float4*)(sp + i);
      T[cseg+i+0][r] = v.x; T[cseg+i+1][r] = v.y;
      T[cseg+i+2][r] = v.z; T[cseg+i+3][r] = v.w;
    }
  }
  __syncthreads();
  const int n = tid>>2, kseg = (tid&3)*16;
  u32 wh[8], wl[8];
  #pragma unroll
  for (int i = 0; i < 8; ++i){
    u16 h0,l0,h1,l1;
    split2(T[n][kseg+2*i], h0, l0);
    split2(T[n][kseg+2*i+1], h1, l1);
    wh[i] = (u32)h0 | ((u32)h1<<16);
    wl[i] = (u32)l0 | ((u32)l1<<16);
  }
  u16* ph = dh + (size_t)(n0+n)*Kst + k0 + kseg;
  u16* pl = dl + (size_t)(n0+n)*Kst + k0 + kseg;
  *(uint4*)(ph)   = make_uint4(wh[0],wh[1],wh[2],wh[3]);
  *(uint4*)(ph+8) = make_uint4(wh[4],wh[5],wh[6],wh[7]);
  *(uint4*)(pl)   = make_uint4(wl[0],wl[1],wl[2],wl[3]);
  *(uint4*)(pl+8) = make_uint4(wl[4],wl[5],wl[6],wl[7]);
}

// ---------------- split-bf16 MFMA GEMM, global_load_lds staging ----------------
template<int BN, int NS, int FLAGS>
__global__ __launch_bounds__(256) void gemm_mfma(
    const u16* __restrict__ Ahi, const u16* __restrict__ Alo,
    const u16* __restrict__ Bhi, const u16* __restrict__ Blo,
    const float* __restrict__ bias, float* __restrict__ C,
    u16* __restrict__ Ohi, u16* __restrict__ Olo,
    u16* __restrict__ Vhi, u16* __restrict__ Vlo,
    int M, int N, int K, int kc){
  constexpr int NA  = 16;
  constexpr int NB  = BN/8;
  constexpr int PER = (NA+NB)/4;
  __shared__ __align__(16) unsigned char As[128*128];
  __shared__ __align__(16) unsigned char Bs[BN*128];
  const int tid = threadIdx.x, wid = tid>>6, lane = tid&63;
  const int li = lane&15, g = lane>>4;
  const int nxb = N/BN;
  const int cpx = gridDim.x >> 3;
  const int bid = blockIdx.x;
  const int wg  = (bid&7)*cpx + (bid>>3);
  const int bx = wg % nxb, by = wg / nxb;
  const int m0 = by*128, n0 = bx*BN;
  const int wr = wid>>1, wc = wid&1;
  const int kbeg = blockIdx.y * kc, kend = kbeg + kc;
  f32x4 acc[4][NS] = {};

  for (int k0 = kbeg; k0 < kend; k0 += 32){
    __syncthreads();
    #pragma unroll
    for (int i = 0; i < PER; ++i){
      const int issue = wid*PER + i;
      const bool isA = issue < NA;
      const int ia = isA ? issue : issue - NA;
      const int c = ia*64 + lane;
      const int row = c>>3, slot = c&7;
      const int sg = slot ^ (row&7);
      const u16* base = isA ? (sg < 4 ? Ahi : Alo) : (sg < 4 ? Bhi : Blo);
      const int gr = (isA ? m0 : n0) + row;
      const u16* gp = base + (size_t)gr*K + k0 + (sg&3)*8;
      unsigned char* lp = (isA ? As : Bs) + ia*1024 + lane*16;
      gload16(gp, lp);
    }
    __syncthreads();
    bf16x8 ah[4], al[4], bh[NS], bl[NS];
    #pragma unroll
    for (int ms = 0; ms < 4; ++ms){
      const int r = wr*64 + ms*16 + li; const int x = (r&7)<<4;
      const unsigned char* p = As + r*128;
      ah[ms] = *(const bf16x8*)(p + ((g*16)^x));
      al[ms] = *(const bf16x8*)(p + ((64 + g*16)^x));
    }
    #pragma unroll
    for (int ns = 0; ns < NS; ++ns){
      const int r = wc*(BN/2) + ns*16 + li; const int x = (r&7)<<4;
      const unsigned char* p = Bs + r*128;
      bh[ns] = *(const bf16x8*)(p + ((g*16)^x));
      bl[ns] = *(const bf16x8*)(p + ((64 + g*16)^x));
    }
    #pragma unroll
    for (int ms = 0; ms < 4; ++ms)
      #pragma unroll
      for (int ns = 0; ns < NS; ++ns){
        acc[ms][ns] = __builtin_amdgcn_mfma_f32_16x16x32_bf16(ah[ms], bh[ns], acc[ms][ns], 0, 0, 0);
        acc[ms][ns] = __builtin_amdgcn_mfma_f32_16x16x32_bf16(ah[ms], bl[ns], acc[ms][ns], 0, 0, 0);
        acc[ms][ns] = __builtin_amdgcn_mfma_f32_16x16x32_bf16(al[ms], bh[ns], acc[ms][ns], 0, 0, 0);
      }
  }
  #pragma unroll
  for (int ms = 0; ms < 4; ++ms){
    #pragma unroll
    for (int ns = 0; ns < NS; ++ns){
      #pragma unroll
      for (int r = 0; r < 4; ++r){
        const int m = m0 + wr*64 + ms*16 + g*4 + r;
        const int n = n0 + wc*(BN/2) + ns*16 + li;
        float val = acc[ms][ns][r];
        if (FLAGS & GF_BIAS) val += bias[n];
        if (FLAGS & GF_RELU) val = fmaxf(val, 0.f);
        if (FLAGS & GF_QKV){
          u16 vh, vl; split2(val, vh, vl);
          if (n < 1024){
            const size_t ix = (size_t)m*1024 + n;
            Ohi[ix] = vh; Olo[ix] = vl;
          } else {
            const size_t ix = ((size_t)(m>>10)*DMOD + (n-1024))*TSEQ + (m&1023);
            Vhi[ix] = vh; Vlo[ix] = vl;
          }
        } else if (FLAGS & GF_SPLIT){
          u16 vh, vl; split2(val, vh, vl);
          const size_t ix = (size_t)m*N + n;
          Ohi[ix] = vh; Olo[ix] = vl;
        } else if (FLAGS & GF_PART){
          C[(size_t)blockIdx.y*M*N + (size_t)m*N + n] = val;
        } else {
          const size_t ix = (size_t)m*N + n;
          if (FLAGS & GF_ACC) val += C[ix];
          C[ix] = val;
        }
      }
    }
  }
}

// ---------------- ksum[b,t,h] = sum_a (k_hi + k_lo) from packed qk buffer ----
__global__ __launch_bounds__(256) void ksum_kernel(const u16* __restrict__ kh_,
    const u16* __restrict__ kl_, float* __restrict__ ks){
  int idx = blockIdx.x*256 + threadIdx.x;
  const size_t base = (size_t)(idx>>3)*1024 + 512 + (idx&7)*DHEAD;
  const u16* ph = kh_ + base;
  const u16* pl = kl_ + base;
  float s = 0.f;
  #pragma unroll
  for (int a = 0; a < DHEAD; a += 8){
    bf16x8 vh = *(const bf16x8*)(ph + a);
    bf16x8 vl = *(const bf16x8*)(pl + a);
    #pragma unroll
    for (int j = 0; j < 8; ++j) s += bf2f((u16)vh[j]) + bf2f((u16)vl[j]);
  }
  ks[idx] = s;
}

// ---- scatter event COUNTS once per launch: cnt[cell] = n0 | (n1<<8), u16/cell --
__global__ __launch_bounds__(256) void scatter_cnt(const int* __restrict__ ab,
    u32* __restrict__ cntw){
  int e = blockIdx.x*256 + threadIdx.x;
  int4 r = *reinterpret_cast<const int4*>(ab + (size_t)e*4);  // et, bi, ki, qi
  const size_t cell = ((size_t)r.y*TSEQ + r.z)*TSEQ + r.w;
  const u32 inc = (r.x ? 0x100u : 1u) << (16*(cell & 1));
  atomicAdd(cntw + (cell >> 1), inc);
}

// ---------------- per-tile attention compute (QK & PV full 3-pass) ------------
// Mixed-fragment rows: per-element row index from rows4[r] (A/B halves).
__device__ __forceinline__ void tile_compute(
    const unsigned char* __restrict__ Klh, const unsigned char* __restrict__ Kll,
    const unsigned char* __restrict__ Vh, const unsigned char* __restrict__ Vl,
    unsigned char* __restrict__ Plh, unsigned char* __restrict__ Pll,
    const float* __restrict__ ksl, const u16* __restrict__ bb,
    float d0, float e1,
    int kt, const int* rows4, int wid, int li, int g,
    const bf16x8* qah, const bf16x8* qal,
    f32x4* oacc, float* mrun, float* srun){
  f32x4 sacc[4] = {};
  #pragma unroll
  for (int jb = 0; jb < 4; ++jb){
    const int rb = (jb*16 + li)*128, x = (li & 7) << 4;
    #pragma unroll
    for (int k2 = 0; k2 < 2; ++k2){
      bf16x8 kfh = *(const bf16x8*)(Klh + rb + ((g*16 + k2*64)^x));
      bf16x8 kfl = *(const bf16x8*)(Kll + rb + ((g*16 + k2*64)^x));
      sacc[jb] = __builtin_amdgcn_mfma_f32_16x16x32_bf16(qah[k2], kfh, sacc[jb], 0, 0, 0);
      sacc[jb] = __builtin_amdgcn_mfma_f32_16x16x32_bf16(qah[k2], kfl, sacc[jb], 0, 0, 0);
      sacc[jb] = __builtin_amdgcn_mfma_f32_16x16x32_bf16(qal[k2], kfh, sacc[jb], 0, 0, 0);
    }
  }
  #pragma unroll
  for (int jb = 0; jb < 4; ++jb){
    const int colg = kt + jb*16 + li;
    const float ksv = ksl[jb*16 + li];
    #pragma unroll
    for (int r = 0; r < 4; ++r){
      const int rowg = rows4[r];
      const u32 c = bb[(size_t)rowg*TSEQ + colg];
      const float bv = fmaf((float)c, d0, (float)(c >> 8) * e1);
      float s = (sacc[jb][r] + bv * ksv) * ATT_SCALE;
      sacc[jb][r] = (colg <= rowg) ? s : -INFINITY;
    }
  }
  #pragma unroll
  for (int r = 0; r < 4; ++r){
    float tm = fmaxf(fmaxf(sacc[0][r], sacc[1][r]), fmaxf(sacc[2][r], sacc[3][r]));
    tm = fmaxf(tm, __shfl_xor(tm, 1));
    tm = fmaxf(tm, __shfl_xor(tm, 2));
    tm = fmaxf(tm, __shfl_xor(tm, 4));
    tm = fmaxf(tm, __shfl_xor(tm, 8));
    const float nm = fmaxf(mrun[r], tm);
    const float fac = __expf(mrun[r] - nm);
    mrun[r] = nm;
    float p0 = __expf(sacc[0][r] - nm);
    float p1 = __expf(sacc[1][r] - nm);
    float p2 = __expf(sacc[2][r] - nm);
    float p3 = __expf(sacc[3][r] - nm);
    float rs = p0 + p1 + p2 + p3;
    rs += __shfl_xor(rs, 1);
    rs += __shfl_xor(rs, 2);
    rs += __shfl_xor(rs, 4);
    rs += __shfl_xor(rs, 8);
    srun[r] = srun[r]*fac + rs;
    oacc[0][r] *= fac; oacc[1][r] *= fac; oacc[2][r] *= fac; oacc[3][r] *= fac;
    const int prow = g*4 + r;
    const int pb = wid*2048 + prow*128, px = (prow & 7) << 4;
    u16 ph0,pl0, ph1,pl1, ph2,pl2, ph3,pl3;
    split2(p0,ph0,pl0); split2(p1,ph1,pl1); split2(p2,ph2,pl2); split2(p3,ph3,pl3);
    *(u16*)(Plh + pb + ((li*2 +  0)^px)) = ph0;
    *(u16*)(Plh + pb + ((li*2 + 32)^px)) = ph1;
    *(u16*)(Plh + pb + ((li*2 + 64)^px)) = ph2;
    *(u16*)(Plh + pb + ((li*2 + 96)^px)) = ph3;
    *(u16*)(Pll + pb + ((li*2 +  0)^px)) = pl0;
    *(u16*)(Pll + pb + ((li*2 + 32)^px)) = pl1;
    *(u16*)(Pll + pb + ((li*2 + 64)^px)) = pl2;
    *(u16*)(Pll + pb + ((li*2 + 96)^px)) = pl3;
  }
  bf16x8 pah[2], pal[2];
  {
    const int pb = wid*2048 + li*128, x = (li & 7) << 4;
    pah[0] = *(const bf16x8*)(Plh + pb + ((g*16     )^x));
    pah[1] = *(const bf16x8*)(Plh + pb + ((g*16 + 64)^x));
    pal[0] = *(const bf16x8*)(Pll + pb + ((g*16     )^x));
    pal[1] = *(const bf16x8*)(Pll + pb + ((g*16 + 64)^x));
  }
  #pragma unroll
  for (int ja = 0; ja < 4; ++ja){
    const int vb = (ja*16 + li)*128, x = (li & 7) << 4;
    #pragma unroll
    for (int k2 = 0; k2 < 2; ++k2){
      bf16x8 vfh = *(const bf16x8*)(Vh + vb + ((g*16 + k2*64)^x));
      bf16x8 vfl = *(const bf16x8*)(Vl + vb + ((g*16 + k2*64)^x));
      oacc[ja] = __builtin_amdgcn_mfma_f32_16x16x32_bf16(pah[k2], vfh, oacc[ja], 0, 0, 0);
      oacc[ja] = __builtin_amdgcn_mfma_f32_16x16x32_bf16(pah[k2], vfl, oacc[ja], 0, 0, 0);
      oacc[ja] = __builtin_amdgcn_mfma_f32_16x16x32_bf16(pal[k2], vfh, oacc[ja], 0, 0, 0);
    }
  }
}

// ---- flash attention: mixed-fragment causal pair, 512 thr = 8 waves ----------
// Block (b,h,p): fragment rows = 8 rows of tile p + 8 rows of tile 15-p.
// A-rows auto-mask (-INF) once kt > qA0. Uniform NB=16-p loop; 2 waves/SIMD.
__global__ __launch_bounds__(512, 1) void attn_split(
    const u16* __restrict__ qkh, const u16* __restrict__ qkl,
    const u16* __restrict__ vth, const u16* __restrict__ vtl,
    const float* __restrict__ ksum, const u16* __restrict__ cnt,
    const float* __restrict__ Ebl, const float* __restrict__ Esl,
    u16* __restrict__ ch_, u16* __restrict__ cl_){
  __shared__ __align__(16) unsigned char Klh[8192], Kll[8192], Vh[8192], Vl[8192];
  __shared__ __align__(16) unsigned char Plh[16384], Pll[16384];
  __shared__ float ksl[64];

  const int bid = blockIdx.x;                 // 256 = b(4) x p(8) x h(8)
  const int h = bid & 7, p = (bid >> 3) & 7, b = bid >> 6;
  const int qA0 = p*64, qB0 = (15-p)*64;
  const int NB = 16 - p;
  const int tid = threadIdx.x, wid = tid >> 6, lane = tid & 63;
  const int li = lane & 15, g = lane >> 4;

  // per-layer bias scalars
  float d0 = 0.f, d1 = 0.f;
  #pragma unroll 8
  for (int a = 0; a < DHEAD; ++a){
    const float e = Esl[a];
    d0 += Ebl[a] * e;
    d1 += Ebl[DHEAD + a] * e;
  }
  const float e1 = d1 - 256.f*d0;

  // mixed-fragment row maps
  const int qrowLi = (li < 8) ? (qA0 + wid*8 + li) : (qB0 + wid*8 + li - 8);
  int rows4[4];
  #pragma unroll
  for (int r = 0; r < 4; ++r){
    const int i16 = g*4 + r;
    rows4[r] = (i16 < 8) ? (qA0 + wid*8 + i16) : (qB0 + wid*8 + i16 - 8);
  }

  bf16x8 qah[2], qal[2];
  {
    const size_t off = (size_t)(b*TSEQ + qrowLi)*1024 + h*DHEAD;
    #pragma unroll
    for (int k2 = 0; k2 < 2; ++k2){
      qah[k2] = *(const bf16x8*)(qkh + off + g*8 + k2*32);
      qal[k2] = *(const bf16x8*)(qkl + off + g*8 + k2*32);
    }
  }

  f32x4 oacc[4] = {};
  float mrun[4] = {-INFINITY,-INFINITY,-INFINITY,-INFINITY};
  float srun[4] = {0.f,0.f,0.f,0.f};

  const int krow = tid >> 3, part8 = tid & 7;   // 512 threads: 8x16B per row
  const int lbase = krow*128;
  const int lslot = ((part8*16) ^ ((krow & 7) << 4));
  const u16* bb = cnt + (size_t)b*TSEQ*TSEQ;

  uint4 rkh, rkl, rvh, rvl;
  float ksr = 0.f;
  auto issue = [&](int kt){
    const size_t koff = (size_t)(b*TSEQ + kt + krow)*1024 + 512 + h*DHEAD + part8*8;
    rkh = *(const uint4*)(qkh + koff);
    rkl = *(const uint4*)(qkl + koff);
    const size_t voff = ((size_t)b*DMOD + h*DHEAD + krow)*TSEQ + kt + part8*8;
    rvh = *(const uint4*)(vth + voff);
    rvl = *(const uint4*)(vtl + voff);
    if (tid < 64) ksr = ksum[(size_t)(b*TSEQ + kt + tid)*HNUM + h];
  };

  issue(0);
  for (int it = 0; it < NB; ++it){
    const int kt = it*64;
    *(uint4*)(Klh + lbase + lslot) = rkh;
    *(uint4*)(Kll + lbase + lslot) = rkl;
    *(uint4*)(Vh  + lbase + lslot) = rvh;
    *(uint4*)(Vl  + lbase + lslot) = rvl;
    if (tid < 64) ksl[tid] = ksr;
    __syncthreads();
    if (it + 1 < NB) issue(kt + 64);          // prefetch under compute
    tile_compute(Klh, Kll, Vh, Vl, Plh, Pll, ksl, bb, d0, e1, kt, rows4,
                 wid, li, g, qah, qal, oacc, mrun, srun);
    __syncthreads();
  }

  // ---- epilogue: normalize, split, store ctx ----
  #pragma unroll
  for (int ja = 0; ja < 4; ++ja){
    #pragma unroll
    for (int r = 0; r < 4; ++r){
      const float val = oacc[ja][r] / srun[r];
      u16 vh, vl; split2(val, vh, vl);
      const size_t ix = (size_t)(b*TSEQ + rows4[r])*DMOD + h*DHEAD + ja*16 + li;
      ch_[ix] = vh; cl_[ix] = vl;
    }
  }
}

extern "C" void kernel_launch(void* const* d_in, const int* in_sizes, int n_in,
                              void* d_out, int out_size, void* d_ws, size_t ws_size,
                              hipStream_t stream){
  const float* states0 = (const float*)d_in[0];
  const int*   ab      = (const int*)d_in[2];
  const float* Wq = (const float*)d_in[3];
  const float* Wk = (const float*)d_in[4];
  const float* Wv = (const float*)d_in[5];
  const float* Wo = (const float*)d_in[6];
  const float* Eb = (const float*)d_in[7];
  const float* Es = (const float*)d_in[8];
  const float* ln1_s = (const float*)d_in[9];
  const float* ln1_b = (const float*)d_in[10];
  const float* ln2_s = (const float*)d_in[11];
  const float* ln2_b = (const float*)d_in[12];
  const float* lno_s = (const float*)d_in[13];
  const float* lno_b = (const float*)d_in[14];
  const float* W1 = (const float*)d_in[15];
  const float* b1 = (const float*)d_in[16];
  const float* W2 = (const float*)d_in[17];
  const float* b2 = (const float*)d_in[18];
  float* out = (float*)d_out;

  char* ws = (char*)d_ws;
  const size_t MB = 1024*1024;
  float* states = (float*)(ws);                       // 0-8 MB f32
  u16* xh  = (u16*)(ws + 8*MB);
  u16* xl  = (u16*)(ws + 12*MB);
  u16* qkh = (u16*)(ws + 16*MB);                      // q|k packed, stride 1024
  u16* qkl = (u16*)(ws + 24*MB);
  u16* vth = (u16*)(ws + 32*MB);                      // V transposed
  u16* vtl = (u16*)(ws + 36*MB);
  u16* cth = (u16*)(ws + 40*MB);
  u16* ctl = (u16*)(ws + 44*MB);
  float* ksum  = (float*)(ws + 48*MB);
  float* part  = (float*)(ws + 48*MB + 131072);       // 16 MB split-K partials
  char*  wA    = ws + 64*MB + 131072;                 // 4 MB wqkv+wo
  char*  wB    = wA + 4*MB;                           // 4 MB w1
  char*  wC    = wB + 4*MB;                           // 4 MB w2
  u16* hh = qkh;
  u16* hl = vth;
  u16* cnt = (u16*)d_out;                             // 8 MB packed counts

  u16* wqkvh = (u16*)(wA);
  u16* wqkvl = (u16*)(wA + 1536*1024);
  u16* woh   = (u16*)(wA + 3*MB);
  u16* wol   = (u16*)(wA + 3*MB + 512*1024);
  u16* w1h   = (u16*)(wB);
  u16* w1l   = (u16*)(wB + 2*MB);
  u16* w2h   = (u16*)(wC);
  u16* w2l   = (u16*)(wC + 2*MB);

  hipMemcpyAsync(states, states0, 8*MB, hipMemcpyDeviceToDevice, stream);
  hipMemsetAsync(d_out, 0, (size_t)BNUM*TSEQ*TSEQ*sizeof(u16), stream);
  scatter_cnt<<<NEVENTS/256, 256, 0, stream>>>(ab, (u32*)d_out);

  const int NROW = BNUM*TSEQ;
  dim3 blk(256);
  for (int l = 0; l < LNUM; ++l){
    wsplit6<<<768, blk, 0, stream>>>(Wq, Wk, Wv, Wo, W1, W2, l,
        wqkvh, wqkvl, woh, wol, w1h, w1l, w2h, w2l);

    // ln1: for l>0 fuses prev layer's W2 split-K reduce + b2[l-1] + residual
    ln_kernel<<<NROW, blk, 0, stream>>>(states,
        (l == 0) ? nullptr : part, (l == 0) ? nullptr : b2 + (size_t)(l-1)*DMOD,
        ln1_s + l*DMOD, ln1_b + l*DMOD, nullptr, xh, xl, 0);
    gemm_mfma<128,4, GF_SPLIT|GF_QKV><<<384, blk, 0, stream>>>(
        xh, xl, wqkvh, wqkvl, nullptr, nullptr, qkh, qkl, vth, vtl, NROW, 1536, DMOD, DMOD);
    ksum_kernel<<<(BNUM*TSEQ*HNUM)/256, blk, 0, stream>>>(qkh, qkl, ksum);
    attn_split<<<BNUM*HNUM*8, dim3(512), 0, stream>>>(qkh, qkl, vth, vtl, ksum, cnt,
        Eb + (size_t)l*2*DHEAD, Es + (size_t)l*DHEAD, cth, ctl);
    gemm_mfma<64,2, GF_PART><<<dim3(256,2), blk, 0, stream>>>(
        cth, ctl, woh, wol, nullptr, part, nullptr, nullptr, nullptr, nullptr, NROW, DMOD, DMOD, DMOD/2);

    // ln2: fuses Wo split-K reduce + residual
    ln_kernel<<<NROW, blk, 0, stream>>>(states, part, nullptr,
        ln2_s + l*DMOD, ln2_b + l*DMOD, nullptr, xh, xl, 0);
    gemm_mfma<128,4, GF_BIAS|GF_RELU|GF_SPLIT><<<512, blk, 0, stream>>>(
        xh, xl, w1h, w1l, b1 + (size_t)l*FDIM, nullptr, hh, hl, nullptr, nullptr, NROW, FDIM, DMOD, DMOD);
    gemm_mfma<64,2, GF_PART><<<dim3(256,2), blk, 0, stream>>>(
        hh, hl, w2h, w2l, nullptr, part, nullptr, nullptr, nullptr, nullptr, NROW, DMOD, FDIM, FDIM/2);
  }
  // final LN fuses layer-5 W2 reduce + b2[5] + residual (overwrites cnt scratch)
  ln_kernel<<<NROW, blk, 0, stream>>>(states, part, b2 + (size_t)(LNUM-1)*DMOD,
      lno_s, lno_b, out, nullptr, nullptr, 1);
}

// Round 20
// 1239.336 us; speedup vs baseline: 1.1537x; 1.1537x over previous
//
#include <hip/hip_runtime.h>
#include <hip/hip_bf16.h>
#include <cstdint>

#define LNUM 6
#define BNUM 4
#define TSEQ 1024
#define DMOD 512
#define HNUM 8
#define FDIM 2048
#define DHEAD 64
#define NEVENTS 65536
#define EPS_LN 1e-3f
#define ATT_SCALE 0.125f

#define GF_ACC 1
#define GF_RELU 2
#define GF_BIAS 4
#define GF_SPLIT 8
#define GF_QKV 16
#define GF_PART 32

typedef float f32x4 __attribute__((ext_vector_type(4)));
typedef short bf16x8 __attribute__((ext_vector_type(8)));
typedef unsigned short u16;
typedef unsigned int u32;

__device__ inline u16 f2bf(float f){
  u32 u = __builtin_bit_cast(u32, f);
  u32 r = (u + 0x7fffu + ((u >> 16) & 1u)) >> 16;
  return (u16)r;
}
__device__ inline float bf2f(u16 u){
  return __builtin_bit_cast(float, (u32)u << 16);
}
__device__ inline void split2(float x, u16 &hi, u16 &lo){
  u16 h = f2bf(x);
  lo = f2bf(x - bf2f(h));
  hi = h;
}
__device__ inline void gload16(const void* g, void* l){
  __builtin_amdgcn_global_load_lds(
      (const __attribute__((address_space(1))) void*)g,
      (__attribute__((address_space(3))) void*)l, 16, 0, 0);
}

// ------- LayerNorm (+fused split-K reduce + optional col-bias + residual) -------
__global__ __launch_bounds__(256) void ln_kernel(float* __restrict__ x,
    const float* __restrict__ part, const float* __restrict__ abias,
    const float* __restrict__ s, const float* __restrict__ bsh,
    float* __restrict__ yf, u16* __restrict__ yh, u16* __restrict__ yl, int mode){
  int row = blockIdx.x, tid = threadIdx.x;
  float* xr = x + (size_t)row * DMOD;
  float2 v = *reinterpret_cast<const float2*>(xr + tid*2);
  if (part){
    const size_t MN = (size_t)BNUM*TSEQ*DMOD;
    const size_t o = (size_t)row*DMOD + tid*2;
    float2 p0 = *reinterpret_cast<const float2*>(part + o);
    float2 p1 = *reinterpret_cast<const float2*>(part + MN + o);
    v.x += p0.x + p1.x; v.y += p0.y + p1.y;
    if (abias){
      v.x += abias[tid*2]; v.y += abias[tid*2+1];
    }
    *reinterpret_cast<float2*>(xr + tid*2) = v;   // materialize residual
  }
  float sum = v.x + v.y, sq = v.x*v.x + v.y*v.y;
  #pragma unroll
  for (int off = 32; off > 0; off >>= 1){
    sum += __shfl_down(sum, off);
    sq  += __shfl_down(sq, off);
  }
  __shared__ float ss[4], sq2[4];
  int wid = tid >> 6;
  if ((tid & 63) == 0){ ss[wid] = sum; sq2[wid] = sq; }
  __syncthreads();
  sum = ss[0]+ss[1]+ss[2]+ss[3];
  sq  = sq2[0]+sq2[1]+sq2[2]+sq2[3];
  float mean = sum * (1.f/DMOD);
  float var  = sq * (1.f/DMOD) - mean*mean;
  float rstd = rsqrtf(var + EPS_LN);
  float2 sc = *reinterpret_cast<const float2*>(s + tid*2);
  float2 bi = *reinterpret_cast<const float2*>(bsh + tid*2);
  float ox = (v.x - mean)*rstd*sc.x + bi.x;
  float oy = (v.y - mean)*rstd*sc.y + bi.y;
  if (mode == 0){
    u16 h0,l0,h1,l1;
    split2(ox,h0,l0); split2(oy,h1,l1);
    *(u32*)(yh + (size_t)row*DMOD + tid*2) = (u32)h0 | ((u32)h1<<16);
    *(u32*)(yl + (size_t)row*DMOD + tid*2) = (u32)l0 | ((u32)l1<<16);
  } else {
    float2 o; o.x = ox; o.y = oy;
    *reinterpret_cast<float2*>(yf + (size_t)row*DMOD + tid*2) = o;
  }
}

// --------- fused weight transpose+split for Wq,Wk,Wv,Wo,W1,W2 (768 blocks) -----
__global__ __launch_bounds__(256) void wsplit6(
    const float* __restrict__ Wq, const float* __restrict__ Wk,
    const float* __restrict__ Wv, const float* __restrict__ Wo,
    const float* __restrict__ W1, const float* __restrict__ W2, int l,
    u16* __restrict__ wqkvh, u16* __restrict__ wqkvl,
    u16* __restrict__ woh,   u16* __restrict__ wol,
    u16* __restrict__ w1h,   u16* __restrict__ w1l,
    u16* __restrict__ w2h,   u16* __restrict__ w2l){
  __shared__ float T[64][65];
  int id = blockIdx.x;
  const float* src; u16 *dh, *dl; int N, Kst, bx, by;
  if (id < 256){
    const int which = id >> 6, sub = id & 63;
    bx = sub & 7; by = sub >> 3; N = 512; Kst = 512;
    if (which == 0){ src = Wq; dh = wqkvh;            dl = wqkvl; }
    else if (which == 1){ src = Wk; dh = wqkvh + 512*512; dl = wqkvl + 512*512; }
    else if (which == 2){ src = Wv; dh = wqkvh + 2*512*512; dl = wqkvl + 2*512*512; }
    else { src = Wo; dh = woh; dl = wol; }
    src += (size_t)l*DMOD*DMOD;
  } else if (id < 512){
    int sub = id - 256;
    bx = sub & 31; by = sub >> 5; N = 2048; Kst = 512;
    src = W1 + (size_t)l*DMOD*FDIM; dh = w1h; dl = w1l;
  } else {
    int sub = id - 512;
    bx = sub & 7; by = sub >> 3; N = 512; Kst = 2048;   // by 0..31 (K=2048 rows)
    src = W2 + (size_t)l*FDIM*DMOD; dh = w2h; dl = w2l;
  }
  const int k0 = by*64, n0 = bx*64;
  const int tid = threadIdx.x;
  {
    const int r = tid>>2, cseg = (tid&3)*16;
    const float* sp = src + (size_t)(k0+r)*N + n0 + cseg;
    #pragma unroll
    for (int i = 0; i < 16; i += 4){
      float4 v = *(const float4*)(sp + i);
      T[cseg+i+0][r] = v.x; T[cseg+i+1][r] = v.y;
      T[cseg+i+2][r] = v.z; T[cseg+i+3][r] = v.w;
    }
  }
  __syncthreads();
  const int n = tid>>2, kseg = (tid&3)*16;
  u32 wh[8], wl[8];
  #pragma unroll
  for (int i = 0; i < 8; ++i){
    u16 h0,l0,h1,l1;
    split2(T[n][kseg+2*i], h0, l0);
    split2(T[n][kseg+2*i+1], h1, l1);
    wh[i] = (u32)h0 | ((u32)h1<<16);
    wl[i] = (u32)l0 | ((u32)l1<<16);
  }
  u16* ph = dh + (size_t)(n0+n)*Kst + k0 + kseg;
  u16* pl = dl + (size_t)(n0+n)*Kst + k0 + kseg;
  *(uint4*)(ph)   = make_uint4(wh[0],wh[1],wh[2],wh[3]);
  *(uint4*)(ph+8) = make_uint4(wh[4],wh[5],wh[6],wh[7]);
  *(uint4*)(pl)   = make_uint4(wl[0],wl[1],wl[2],wl[3]);
  *(uint4*)(pl+8) = make_uint4(wl[4],wl[5],wl[6],wl[7]);
}

// ---------------- split-bf16 MFMA GEMM, global_load_lds staging ----------------
template<int BN, int NS, int FLAGS>
__global__ __launch_bounds__(256) void gemm_mfma(
    const u16* __restrict__ Ahi, const u16* __restrict__ Alo,
    const u16* __restrict__ Bhi, const u16* __restrict__ Blo,
    const float* __restrict__ bias, float* __restrict__ C,
    u16* __restrict__ Ohi, u16* __restrict__ Olo,
    u16* __restrict__ Vhi, u16* __restrict__ Vlo,
    int M, int N, int K, int kc){
  constexpr int NA  = 16;
  constexpr int NB  = BN/8;
  constexpr int PER = (NA+NB)/4;
  __shared__ __align__(16) unsigned char As[128*128];
  __shared__ __align__(16) unsigned char Bs[BN*128];
  const int tid = threadIdx.x, wid = tid>>6, lane = tid&63;
  const int li = lane&15, g = lane>>4;
  const int nxb = N/BN;
  const int cpx = gridDim.x >> 3;
  const int bid = blockIdx.x;
  const int wg  = (bid&7)*cpx + (bid>>3);
  const int bx = wg % nxb, by = wg / nxb;
  const int m0 = by*128, n0 = bx*BN;
  const int wr = wid>>1, wc = wid&1;
  const int kbeg = blockIdx.y * kc, kend = kbeg + kc;
  f32x4 acc[4][NS] = {};

  for (int k0 = kbeg; k0 < kend; k0 += 32){
    __syncthreads();
    #pragma unroll
    for (int i = 0; i < PER; ++i){
      const int issue = wid*PER + i;
      const bool isA = issue < NA;
      const int ia = isA ? issue : issue - NA;
      const int c = ia*64 + lane;
      const int row = c>>3, slot = c&7;
      const int sg = slot ^ (row&7);
      const u16* base = isA ? (sg < 4 ? Ahi : Alo) : (sg < 4 ? Bhi : Blo);
      const int gr = (isA ? m0 : n0) + row;
      const u16* gp = base + (size_t)gr*K + k0 + (sg&3)*8;
      unsigned char* lp = (isA ? As : Bs) + ia*1024 + lane*16;
      gload16(gp, lp);
    }
    __syncthreads();
    bf16x8 ah[4], al[4], bh[NS], bl[NS];
    #pragma unroll
    for (int ms = 0; ms < 4; ++ms){
      const int r = wr*64 + ms*16 + li; const int x = (r&7)<<4;
      const unsigned char* p = As + r*128;
      ah[ms] = *(const bf16x8*)(p + ((g*16)^x));
      al[ms] = *(const bf16x8*)(p + ((64 + g*16)^x));
    }
    #pragma unroll
    for (int ns = 0; ns < NS; ++ns){
      const int r = wc*(BN/2) + ns*16 + li; const int x = (r&7)<<4;
      const unsigned char* p = Bs + r*128;
      bh[ns] = *(const bf16x8*)(p + ((g*16)^x));
      bl[ns] = *(const bf16x8*)(p + ((64 + g*16)^x));
    }
    #pragma unroll
    for (int ms = 0; ms < 4; ++ms)
      #pragma unroll
      for (int ns = 0; ns < NS; ++ns){
        acc[ms][ns] = __builtin_amdgcn_mfma_f32_16x16x32_bf16(ah[ms], bh[ns], acc[ms][ns], 0, 0, 0);
        acc[ms][ns] = __builtin_amdgcn_mfma_f32_16x16x32_bf16(ah[ms], bl[ns], acc[ms][ns], 0, 0, 0);
        acc[ms][ns] = __builtin_amdgcn_mfma_f32_16x16x32_bf16(al[ms], bh[ns], acc[ms][ns], 0, 0, 0);
      }
  }
  #pragma unroll
  for (int ms = 0; ms < 4; ++ms){
    #pragma unroll
    for (int ns = 0; ns < NS; ++ns){
      #pragma unroll
      for (int r = 0; r < 4; ++r){
        const int m = m0 + wr*64 + ms*16 + g*4 + r;
        const int n = n0 + wc*(BN/2) + ns*16 + li;
        float val = acc[ms][ns][r];
        if (FLAGS & GF_BIAS) val += bias[n];
        if (FLAGS & GF_RELU) val = fmaxf(val, 0.f);
        if (FLAGS & GF_QKV){
          u16 vh, vl; split2(val, vh, vl);
          if (n < 1024){
            const size_t ix = (size_t)m*1024 + n;
            Ohi[ix] = vh; Olo[ix] = vl;
          } else {
            const size_t ix = ((size_t)(m>>10)*DMOD + (n-1024))*TSEQ + (m&1023);
            Vhi[ix] = vh; Vlo[ix] = vl;
          }
        } else if (FLAGS & GF_SPLIT){
          u16 vh, vl; split2(val, vh, vl);
          const size_t ix = (size_t)m*N + n;
          Ohi[ix] = vh; Olo[ix] = vl;
        } else if (FLAGS & GF_PART){
          C[(size_t)blockIdx.y*M*N + (size_t)m*N + n] = val;
        } else {
          const size_t ix = (size_t)m*N + n;
          if (FLAGS & GF_ACC) val += C[ix];
          C[ix] = val;
        }
      }
    }
  }
}

// ---------------- ksum[b,t,h] = sum_a (k_hi + k_lo) from packed qk buffer ----
__global__ __launch_bounds__(256) void ksum_kernel(const u16* __restrict__ kh_,
    const u16* __restrict__ kl_, float* __restrict__ ks){
  int idx = blockIdx.x*256 + threadIdx.x;
  const size_t base = (size_t)(idx>>3)*1024 + 512 + (idx&7)*DHEAD;
  const u16* ph = kh_ + base;
  const u16* pl = kl_ + base;
  float s = 0.f;
  #pragma unroll
  for (int a = 0; a < DHEAD; a += 8){
    bf16x8 vh = *(const bf16x8*)(ph + a);
    bf16x8 vl = *(const bf16x8*)(pl + a);
    #pragma unroll
    for (int j = 0; j < 8; ++j) s += bf2f((u16)vh[j]) + bf2f((u16)vl[j]);
  }
  ks[idx] = s;
}

// ---- scatter event COUNTS once per launch: cnt[cell] = n0 | (n1<<8), u16/cell --
__global__ __launch_bounds__(256) void scatter_cnt(const int* __restrict__ ab,
    u32* __restrict__ cntw){
  int e = blockIdx.x*256 + threadIdx.x;
  int4 r = *reinterpret_cast<const int4*>(ab + (size_t)e*4);  // et, bi, ki, qi
  const size_t cell = ((size_t)r.y*TSEQ + r.z)*TSEQ + r.w;
  const u32 inc = (r.x ? 0x100u : 1u) << (16*(cell & 1));
  atomicAdd(cntw + (cell >> 1), inc);
}

// ---------------- per-tile attention compute (QK & PV full 3-pass) ------------
// bias decode: c = n0 + 256*n1 (exact in f32) -> bv = c*d0 + n1*(d1-256*d0).
__device__ __forceinline__ void tile_compute(
    const unsigned char* __restrict__ Klh, const unsigned char* __restrict__ Kll,
    const unsigned char* __restrict__ Vh, const unsigned char* __restrict__ Vl,
    unsigned char* __restrict__ Plh, unsigned char* __restrict__ Pll,
    const float* __restrict__ ksl, const u16* __restrict__ bb,
    float d0, float e1,
    int kt, int rowg0, int wid, int li, int g,
    const bf16x8* qah, const bf16x8* qal,
    f32x4* oacc, float* mrun, float* srun){
  f32x4 sacc[4] = {};
  #pragma unroll
  for (int jb = 0; jb < 4; ++jb){
    const int rb = (jb*16 + li)*128, x = (li & 7) << 4;
    #pragma unroll
    for (int k2 = 0; k2 < 2; ++k2){
      bf16x8 kfh = *(const bf16x8*)(Klh + rb + ((g*16 + k2*64)^x));
      bf16x8 kfl = *(const bf16x8*)(Kll + rb + ((g*16 + k2*64)^x));
      sacc[jb] = __builtin_amdgcn_mfma_f32_16x16x32_bf16(qah[k2], kfh, sacc[jb], 0, 0, 0);
      sacc[jb] = __builtin_amdgcn_mfma_f32_16x16x32_bf16(qah[k2], kfl, sacc[jb], 0, 0, 0);
      sacc[jb] = __builtin_amdgcn_mfma_f32_16x16x32_bf16(qal[k2], kfh, sacc[jb], 0, 0, 0);
    }
  }
  #pragma unroll
  for (int jb = 0; jb < 4; ++jb){
    const int colg = kt + jb*16 + li;
    const float ksv = ksl[jb*16 + li];
    #pragma unroll
    for (int r = 0; r < 4; ++r){
      const int rowg = rowg0 + r;
      const u32 c = bb[(size_t)rowg*TSEQ + colg];
      const float bv = fmaf((float)c, d0, (float)(c >> 8) * e1);
      float s = (sacc[jb][r] + bv * ksv) * ATT_SCALE;
      sacc[jb][r] = (colg <= rowg) ? s : -INFINITY;
    }
  }
  #pragma unroll
  for (int r = 0; r < 4; ++r){
    float tm = fmaxf(fmaxf(sacc[0][r], sacc[1][r]), fmaxf(sacc[2][r], sacc[3][r]));
    tm = fmaxf(tm, __shfl_xor(tm, 1));
    tm = fmaxf(tm, __shfl_xor(tm, 2));
    tm = fmaxf(tm, __shfl_xor(tm, 4));
    tm = fmaxf(tm, __shfl_xor(tm, 8));
    const float nm = fmaxf(mrun[r], tm);
    const float fac = __expf(mrun[r] - nm);
    mrun[r] = nm;
    float p0 = __expf(sacc[0][r] - nm);
    float p1 = __expf(sacc[1][r] - nm);
    float p2 = __expf(sacc[2][r] - nm);
    float p3 = __expf(sacc[3][r] - nm);
    float rs = p0 + p1 + p2 + p3;
    rs += __shfl_xor(rs, 1);
    rs += __shfl_xor(rs, 2);
    rs += __shfl_xor(rs, 4);
    rs += __shfl_xor(rs, 8);
    srun[r] = srun[r]*fac + rs;
    oacc[0][r] *= fac; oacc[1][r] *= fac; oacc[2][r] *= fac; oacc[3][r] *= fac;
    const int prow = g*4 + r;
    const int pb = wid*2048 + prow*128, px = (prow & 7) << 4;
    u16 ph0,pl0, ph1,pl1, ph2,pl2, ph3,pl3;
    split2(p0,ph0,pl0); split2(p1,ph1,pl1); split2(p2,ph2,pl2); split2(p3,ph3,pl3);
    *(u16*)(Plh + pb + ((li*2 +  0)^px)) = ph0;
    *(u16*)(Plh + pb + ((li*2 + 32)^px)) = ph1;
    *(u16*)(Plh + pb + ((li*2 + 64)^px)) = ph2;
    *(u16*)(Plh + pb + ((li*2 + 96)^px)) = ph3;
    *(u16*)(Pll + pb + ((li*2 +  0)^px)) = pl0;
    *(u16*)(Pll + pb + ((li*2 + 32)^px)) = pl1;
    *(u16*)(Pll + pb + ((li*2 + 64)^px)) = pl2;
    *(u16*)(Pll + pb + ((li*2 + 96)^px)) = pl3;
  }
  bf16x8 pah[2], pal[2];
  {
    const int pb = wid*2048 + li*128, x = (li & 7) << 4;
    pah[0] = *(const bf16x8*)(Plh + pb + ((g*16     )^x));
    pah[1] = *(const bf16x8*)(Plh + pb + ((g*16 + 64)^x));
    pal[0] = *(const bf16x8*)(Pll + pb + ((g*16     )^x));
    pal[1] = *(const bf16x8*)(Pll + pb + ((g*16 + 64)^x));
  }
  #pragma unroll
  for (int ja = 0; ja < 4; ++ja){
    const int vb = (ja*16 + li)*128, x = (li & 7) << 4;
    #pragma unroll
    for (int k2 = 0; k2 < 2; ++k2){
      bf16x8 vfh = *(const bf16x8*)(Vh + vb + ((g*16 + k2*64)^x));
      bf16x8 vfl = *(const bf16x8*)(Vl + vb + ((g*16 + k2*64)^x));
      oacc[ja] = __builtin_amdgcn_mfma_f32_16x16x32_bf16(pah[k2], vfh, oacc[ja], 0, 0, 0);
      oacc[ja] = __builtin_amdgcn_mfma_f32_16x16x32_bf16(pah[k2], vfl, oacc[ja], 0, 0, 0);
      oacc[ja] = __builtin_amdgcn_mfma_f32_16x16x32_bf16(pal[k2], vfh, oacc[ja], 0, 0, 0);
    }
  }
}

// ---------------- flash attention, causal-paired blocks (R13/R18 structure) ----
// XCD-local mapping: bid&7 = h so p-blocks sharing (b,h) streams share an XCD L2.
__global__ __launch_bounds__(256) void attn_split(
    const u16* __restrict__ qkh, const u16* __restrict__ qkl,
    const u16* __restrict__ vth, const u16* __restrict__ vtl,
    const float* __restrict__ ksum, const u16* __restrict__ cnt,
    const float* __restrict__ Ebl, const float* __restrict__ Esl,
    u16* __restrict__ ch_, u16* __restrict__ cl_){
  __shared__ __align__(16) unsigned char Klh[8192], Kll[8192], Vh[8192], Vl[8192];
  __shared__ __align__(16) unsigned char Plh[8192], Pll[8192];
  __shared__ float ksl[64];

  const int bid = blockIdx.x;                 // 256 = b(4) x p(8) x h(8)
  const int h = bid & 7, p = (bid >> 3) & 7, b = bid >> 6;
  const int qA0 = p*64, qB0 = (15-p)*64;
  const int tid = threadIdx.x, wid = tid >> 6, lane = tid & 63;
  const int li = lane & 15, g = lane >> 4;
  const int rowA0 = qA0 + wid*16 + g*4;
  const int rowB0 = qB0 + wid*16 + g*4;

  // per-layer bias scalars (redundant per thread; broadcast loads)
  float d0 = 0.f, d1 = 0.f;
  #pragma unroll 8
  for (int a = 0; a < DHEAD; ++a){
    const float e = Esl[a];
    d0 += Ebl[a] * e;
    d1 += Ebl[DHEAD + a] * e;
  }
  const float e1 = d1 - 256.f*d0;

  bf16x8 qahA[2], qalA[2], qahB[2], qalB[2];
  {
    const size_t offA = (size_t)(b*TSEQ + qA0 + wid*16 + li)*1024 + h*DHEAD;
    const size_t offB = (size_t)(b*TSEQ + qB0 + wid*16 + li)*1024 + h*DHEAD;
    #pragma unroll
    for (int k2 = 0; k2 < 2; ++k2){
      qahA[k2] = *(const bf16x8*)(qkh + offA + g*8 + k2*32);
      qalA[k2] = *(const bf16x8*)(qkl + offA + g*8 + k2*32);
      qahB[k2] = *(const bf16x8*)(qkh + offB + g*8 + k2*32);
      qalB[k2] = *(const bf16x8*)(qkl + offB + g*8 + k2*32);
    }
  }

  f32x4 oaccA[4] = {}, oaccB[4] = {};
  float mrunA[4] = {-INFINITY,-INFINITY,-INFINITY,-INFINITY};
  float mrunB[4] = {-INFINITY,-INFINITY,-INFINITY,-INFINITY};
  float srunA[4] = {0.f,0.f,0.f,0.f};
  float srunB[4] = {0.f,0.f,0.f,0.f};

  const int krow = tid >> 2, part = tid & 3;
  const int lbase = krow*128, lx = (krow & 7) << 4;
  const u16* bb = cnt + (size_t)b*TSEQ*TSEQ;

  uint4 rk0, rk1, rk2, rk3, rv0, rv1, rv2, rv3;
  float ksr = 0.f;
  auto issue = [&](int kt){
    const size_t koff = (size_t)(b*TSEQ + kt + krow)*1024 + 512 + h*DHEAD + part*16;
    rk0 = *(const uint4*)(qkh + koff);
    rk1 = *(const uint4*)(qkh + koff + 8);
    rk2 = *(const uint4*)(qkl + koff);
    rk3 = *(const uint4*)(qkl + koff + 8);
    const size_t voff = ((size_t)b*DMOD + h*DHEAD + krow)*TSEQ + kt + part*16;
    rv0 = *(const uint4*)(vth + voff);
    rv1 = *(const uint4*)(vth + voff + 8);
    rv2 = *(const uint4*)(vtl + voff);
    rv3 = *(const uint4*)(vtl + voff + 8);
    if (tid < 64) ksr = ksum[(size_t)(b*TSEQ + kt + tid)*HNUM + h];
  };

  issue(0);
  for (int kt = 0; kt <= qB0; kt += 64){
    *(uint4*)(Klh + lbase + ((part*32     )^lx)) = rk0;
    *(uint4*)(Klh + lbase + ((part*32 + 16)^lx)) = rk1;
    *(uint4*)(Kll + lbase + ((part*32     )^lx)) = rk2;
    *(uint4*)(Kll + lbase + ((part*32 + 16)^lx)) = rk3;
    *(uint4*)(Vh  + lbase + ((part*32     )^lx)) = rv0;
    *(uint4*)(Vh  + lbase + ((part*32 + 16)^lx)) = rv1;
    *(uint4*)(Vl  + lbase + ((part*32     )^lx)) = rv2;
    *(uint4*)(Vl  + lbase + ((part*32 + 16)^lx)) = rv3;
    if (tid < 64) ksl[tid] = ksr;
    __syncthreads();
    if (kt + 64 <= qB0) issue(kt + 64);   // prefetch next tile under compute
    tile_compute(Klh, Kll, Vh, Vl, Plh, Pll, ksl, bb, d0, e1, kt, rowB0, wid, li, g,
                 qahB, qalB, oaccB, mrunB, srunB);
    if (kt <= qA0)
      tile_compute(Klh, Kll, Vh, Vl, Plh, Pll, ksl, bb, d0, e1, kt, rowA0, wid, li, g,
                   qahA, qalA, oaccA, mrunA, srunA);
    __syncthreads();
  }

  // ---- epilogue: normalize, split, store ctx for both tiles ----
  #pragma unroll
  for (int ja = 0; ja < 4; ++ja){
    #pragma unroll
    for (int r = 0; r < 4; ++r){
      {
        const float val = oaccB[ja][r] / srunB[r];
        u16 vh, vl; split2(val, vh, vl);
        const size_t ix = (size_t)(b*TSEQ + rowB0 + r)*DMOD + h*DHEAD + ja*16 + li;
        ch_[ix] = vh; cl_[ix] = vl;
      }
      {
        const float val = oaccA[ja][r] / srunA[r];
        u16 vh, vl; split2(val, vh, vl);
        const size_t ix = (size_t)(b*TSEQ + rowA0 + r)*DMOD + h*DHEAD + ja*16 + li;
        ch_[ix] = vh; cl_[ix] = vl;
      }
    }
  }
}

extern "C" void kernel_launch(void* const* d_in, const int* in_sizes, int n_in,
                              void* d_out, int out_size, void* d_ws, size_t ws_size,
                              hipStream_t stream){
  const float* states0 = (const float*)d_in[0];
  const int*   ab      = (const int*)d_in[2];
  const float* Wq = (const float*)d_in[3];
  const float* Wk = (const float*)d_in[4];
  const float* Wv = (const float*)d_in[5];
  const float* Wo = (const float*)d_in[6];
  const float* Eb = (const float*)d_in[7];
  const float* Es = (const float*)d_in[8];
  const float* ln1_s = (const float*)d_in[9];
  const float* ln1_b = (const float*)d_in[10];
  const float* ln2_s = (const float*)d_in[11];
  const float* ln2_b = (const float*)d_in[12];
  const float* lno_s = (const float*)d_in[13];
  const float* lno_b = (const float*)d_in[14];
  const float* W1 = (const float*)d_in[15];
  const float* b1 = (const float*)d_in[16];
  const float* W2 = (const float*)d_in[17];
  const float* b2 = (const float*)d_in[18];
  float* out = (float*)d_out;

  char* ws = (char*)d_ws;
  const size_t MB = 1024*1024;
  float* states = (float*)(ws);                       // 0-8 MB f32
  u16* xh  = (u16*)(ws + 8*MB);
  u16* xl  = (u16*)(ws + 12*MB);
  u16* qkh = (u16*)(ws + 16*MB);                      // q|k packed, stride 1024
  u16* qkl = (u16*)(ws + 24*MB);
  u16* vth = (u16*)(ws + 32*MB);                      // V transposed
  u16* vtl = (u16*)(ws + 36*MB);
  u16* cth = (u16*)(ws + 40*MB);
  u16* ctl = (u16*)(ws + 44*MB);
  float* ksum  = (float*)(ws + 48*MB);
  float* part  = (float*)(ws + 48*MB + 131072);       // 16 MB split-K partials
  char*  wA    = ws + 64*MB + 131072;                 // 4 MB wqkv+wo
  char*  wB    = wA + 4*MB;                           // 4 MB w1
  char*  wC    = wB + 4*MB;                           // 4 MB w2
  u16* hh = qkh;
  u16* hl = vth;
  u16* cnt = (u16*)d_out;                             // 8 MB packed counts

  u16* wqkvh = (u16*)(wA);
  u16* wqkvl = (u16*)(wA + 1536*1024);
  u16* woh   = (u16*)(wA + 3*MB);
  u16* wol   = (u16*)(wA + 3*MB + 512*1024);
  u16* w1h   = (u16*)(wB);
  u16* w1l   = (u16*)(wB + 2*MB);
  u16* w2h   = (u16*)(wC);
  u16* w2l   = (u16*)(wC + 2*MB);

  hipMemcpyAsync(states, states0, 8*MB, hipMemcpyDeviceToDevice, stream);
  hipMemsetAsync(d_out, 0, (size_t)BNUM*TSEQ*TSEQ*sizeof(u16), stream);
  scatter_cnt<<<NEVENTS/256, 256, 0, stream>>>(ab, (u32*)d_out);

  const int NROW = BNUM*TSEQ;
  dim3 blk(256);
  for (int l = 0; l < LNUM; ++l){
    wsplit6<<<768, blk, 0, stream>>>(Wq, Wk, Wv, Wo, W1, W2, l,
        wqkvh, wqkvl, woh, wol, w1h, w1l, w2h, w2l);

    // ln1: for l>0 fuses prev layer's W2 split-K reduce + b2[l-1] + residual
    ln_kernel<<<NROW, blk, 0, stream>>>(states,
        (l == 0) ? nullptr : part, (l == 0) ? nullptr : b2 + (size_t)(l-1)*DMOD,
        ln1_s + l*DMOD, ln1_b + l*DMOD, nullptr, xh, xl, 0);
    gemm_mfma<128,4, GF_SPLIT|GF_QKV><<<384, blk, 0, stream>>>(
        xh, xl, wqkvh, wqkvl, nullptr, nullptr, qkh, qkl, vth, vtl, NROW, 1536, DMOD, DMOD);
    ksum_kernel<<<(BNUM*TSEQ*HNUM)/256, blk, 0, stream>>>(qkh, qkl, ksum);
    attn_split<<<BNUM*HNUM*8, blk, 0, stream>>>(qkh, qkl, vth, vtl, ksum, cnt,
        Eb + (size_t)l*2*DHEAD, Es + (size_t)l*DHEAD, cth, ctl);
    gemm_mfma<64,2, GF_PART><<<dim3(256,2), blk, 0, stream>>>(
        cth, ctl, woh, wol, nullptr, part, nullptr, nullptr, nullptr, nullptr, NROW, DMOD, DMOD, DMOD/2);

    // ln2: fuses Wo split-K reduce + residual
    ln_kernel<<<NROW, blk, 0, stream>>>(states, part, nullptr,
        ln2_s + l*DMOD, ln2_b + l*DMOD, nullptr, xh, xl, 0);
    gemm_mfma<128,4, GF_BIAS|GF_RELU|GF_SPLIT><<<512, blk, 0, stream>>>(
        xh, xl, w1h, w1l, b1 + (size_t)l*FDIM, nullptr, hh, hl, nullptr, nullptr, NROW, FDIM, DMOD, DMOD);
    gemm_mfma<64,2, GF_PART><<<dim3(256,2), blk, 0, stream>>>(
        hh, hl, w2h, w2l, nullptr, part, nullptr, nullptr, nullptr, nullptr, NROW, DMOD, FDIM, FDIM/2);
  }
  // final LN fuses layer-5 W2 reduce + b2[5] + residual (overwrites cnt scratch)
  ln_kernel<<<NROW, blk, 0, stream>>>(states, part, b2 + (size_t)(LNUM-1)*DMOD,
      lno_s, lno_b, out, nullptr, nullptr, 1);
}

// Round 21
// 1226.746 us; speedup vs baseline: 1.1655x; 1.0103x over previous
//
#include <hip/hip_runtime.h>
#include <hip/hip_bf16.h>
#include <cstdint>

#define LNUM 6
#define BNUM 4
#define TSEQ 1024
#define DMOD 512
#define HNUM 8
#define FDIM 2048
#define DHEAD 64
#define NEVENTS 65536
#define EPS_LN 1e-3f
#define ATT_SCALE 0.125f

#define GF_ACC 1
#define GF_RELU 2
#define GF_BIAS 4
#define GF_SPLIT 8
#define GF_QKV 16
#define GF_PART 32

typedef float f32x4 __attribute__((ext_vector_type(4)));
typedef short bf16x8 __attribute__((ext_vector_type(8)));
typedef unsigned short u16;
typedef unsigned int u32;

__device__ inline u16 f2bf(float f){
  u32 u = __builtin_bit_cast(u32, f);
  u32 r = (u + 0x7fffu + ((u >> 16) & 1u)) >> 16;
  return (u16)r;
}
__device__ inline float bf2f(u16 u){
  return __builtin_bit_cast(float, (u32)u << 16);
}
__device__ inline void split2(float x, u16 &hi, u16 &lo){
  u16 h = f2bf(x);
  lo = f2bf(x - bf2f(h));
  hi = h;
}
__device__ inline void gload16(const void* g, void* l){
  __builtin_amdgcn_global_load_lds(
      (const __attribute__((address_space(1))) void*)g,
      (__attribute__((address_space(3))) void*)l, 16, 0, 0);
}

// ------- LayerNorm (+fused split-K reduce + optional col-bias + residual) -------
__global__ __launch_bounds__(256) void ln_kernel(float* __restrict__ x,
    const float* __restrict__ part, const float* __restrict__ abias,
    const float* __restrict__ s, const float* __restrict__ bsh,
    float* __restrict__ yf, u16* __restrict__ yh, u16* __restrict__ yl, int mode){
  int row = blockIdx.x, tid = threadIdx.x;
  float* xr = x + (size_t)row * DMOD;
  float2 v = *reinterpret_cast<const float2*>(xr + tid*2);
  if (part){
    const size_t MN = (size_t)BNUM*TSEQ*DMOD;
    const size_t o = (size_t)row*DMOD + tid*2;
    float2 p0 = *reinterpret_cast<const float2*>(part + o);
    float2 p1 = *reinterpret_cast<const float2*>(part + MN + o);
    v.x += p0.x + p1.x; v.y += p0.y + p1.y;
    if (abias){
      v.x += abias[tid*2]; v.y += abias[tid*2+1];
    }
    *reinterpret_cast<float2*>(xr + tid*2) = v;   // materialize residual
  }
  float sum = v.x + v.y, sq = v.x*v.x + v.y*v.y;
  #pragma unroll
  for (int off = 32; off > 0; off >>= 1){
    sum += __shfl_down(sum, off);
    sq  += __shfl_down(sq, off);
  }
  __shared__ float ss[4], sq2[4];
  int wid = tid >> 6;
  if ((tid & 63) == 0){ ss[wid] = sum; sq2[wid] = sq; }
  __syncthreads();
  sum = ss[0]+ss[1]+ss[2]+ss[3];
  sq  = sq2[0]+sq2[1]+sq2[2]+sq2[3];
  float mean = sum * (1.f/DMOD);
  float var  = sq * (1.f/DMOD) - mean*mean;
  float rstd = rsqrtf(var + EPS_LN);
  float2 sc = *reinterpret_cast<const float2*>(s + tid*2);
  float2 bi = *reinterpret_cast<const float2*>(bsh + tid*2);
  float ox = (v.x - mean)*rstd*sc.x + bi.x;
  float oy = (v.y - mean)*rstd*sc.y + bi.y;
  if (mode == 0){
    u16 h0,l0,h1,l1;
    split2(ox,h0,l0); split2(oy,h1,l1);
    *(u32*)(yh + (size_t)row*DMOD + tid*2) = (u32)h0 | ((u32)h1<<16);
    *(u32*)(yl + (size_t)row*DMOD + tid*2) = (u32)l0 | ((u32)l1<<16);
  } else {
    float2 o; o.x = ox; o.y = oy;
    *reinterpret_cast<float2*>(yf + (size_t)row*DMOD + tid*2) = o;
  }
}

// --------- fused weight transpose+split for Wq,Wk,Wv,Wo,W1,W2 (768 blocks) -----
__global__ __launch_bounds__(256) void wsplit6(
    const float* __restrict__ Wq, const float* __restrict__ Wk,
    const float* __restrict__ Wv, const float* __restrict__ Wo,
    const float* __restrict__ W1, const float* __restrict__ W2, int l,
    u16* __restrict__ wqkvh, u16* __restrict__ wqkvl,
    u16* __restrict__ woh,   u16* __restrict__ wol,
    u16* __restrict__ w1h,   u16* __restrict__ w1l,
    u16* __restrict__ w2h,   u16* __restrict__ w2l){
  __shared__ float T[64][65];
  int id = blockIdx.x;
  const float* src; u16 *dh, *dl; int N, Kst, bx, by;
  if (id < 256){
    const int which = id >> 6, sub = id & 63;
    bx = sub & 7; by = sub >> 3; N = 512; Kst = 512;
    if (which == 0){ src = Wq; dh = wqkvh;            dl = wqkvl; }
    else if (which == 1){ src = Wk; dh = wqkvh + 512*512; dl = wqkvl + 512*512; }
    else if (which == 2){ src = Wv; dh = wqkvh + 2*512*512; dl = wqkvl + 2*512*512; }
    else { src = Wo; dh = woh; dl = wol; }
    src += (size_t)l*DMOD*DMOD;
  } else if (id < 512){
    int sub = id - 256;
    bx = sub & 31; by = sub >> 5; N = 2048; Kst = 512;
    src = W1 + (size_t)l*DMOD*FDIM; dh = w1h; dl = w1l;
  } else {
    int sub = id - 512;
    bx = sub & 7; by = sub >> 3; N = 512; Kst = 2048;   // by 0..31 (K=2048 rows)
    src = W2 + (size_t)l*FDIM*DMOD; dh = w2h; dl = w2l;
  }
  const int k0 = by*64, n0 = bx*64;
  const int tid = threadIdx.x;
  {
    const int r = tid>>2, cseg = (tid&3)*16;
    const float* sp = src + (size_t)(k0+r)*N + n0 + cseg;
    #pragma unroll
    for (int i = 0; i < 16; i += 4){
      float4 v = *(const float4*)(sp + i);
      T[cseg+i+0][r] = v.x; T[cseg+i+1][r] = v.y;
      T[cseg+i+2][r] = v.z; T[cseg+i+3][r] = v.w;
    }
  }
  __syncthreads();
  const int n = tid>>2, kseg = (tid&3)*16;
  u32 wh[8], wl[8];
  #pragma unroll
  for (int i = 0; i < 8; ++i){
    u16 h0,l0,h1,l1;
    split2(T[n][kseg+2*i], h0, l0);
    split2(T[n][kseg+2*i+1], h1, l1);
    wh[i] = (u32)h0 | ((u32)h1<<16);
    wl[i] = (u32)l0 | ((u32)l1<<16);
  }
  u16* ph = dh + (size_t)(n0+n)*Kst + k0 + kseg;
  u16* pl = dl + (size_t)(n0+n)*Kst + k0 + kseg;
  *(uint4*)(ph)   = make_uint4(wh[0],wh[1],wh[2],wh[3]);
  *(uint4*)(ph+8) = make_uint4(wh[4],wh[5],wh[6],wh[7]);
  *(uint4*)(pl)   = make_uint4(wl[0],wl[1],wl[2],wl[3]);
  *(uint4*)(pl+8) = make_uint4(wl[4],wl[5],wl[6],wl[7]);
}

// ---------------- split-bf16 MFMA GEMM, global_load_lds staging ----------------
template<int BN, int NS, int FLAGS>
__global__ __launch_bounds__(256) void gemm_mfma(
    const u16* __restrict__ Ahi, const u16* __restrict__ Alo,
    const u16* __restrict__ Bhi, const u16* __restrict__ Blo,
    const float* __restrict__ bias, float* __restrict__ C,
    u16* __restrict__ Ohi, u16* __restrict__ Olo,
    u16* __restrict__ Vhi, u16* __restrict__ Vlo,
    int M, int N, int K, int kc){
  constexpr int NA  = 16;
  constexpr int NB  = BN/8;
  constexpr int PER = (NA+NB)/4;
  __shared__ __align__(16) unsigned char As[128*128];
  __shared__ __align__(16) unsigned char Bs[BN*128];
  const int tid = threadIdx.x, wid = tid>>6, lane = tid&63;
  const int li = lane&15, g = lane>>4;
  const int nxb = N/BN;
  const int cpx = gridDim.x >> 3;
  const int bid = blockIdx.x;
  const int wg  = (bid&7)*cpx + (bid>>3);
  const int bx = wg % nxb, by = wg / nxb;
  const int m0 = by*128, n0 = bx*BN;
  const int wr = wid>>1, wc = wid&1;
  const int kbeg = blockIdx.y * kc, kend = kbeg + kc;
  f32x4 acc[4][NS] = {};

  for (int k0 = kbeg; k0 < kend; k0 += 32){
    __syncthreads();
    #pragma unroll
    for (int i = 0; i < PER; ++i){
      const int issue = wid*PER + i;
      const bool isA = issue < NA;
      const int ia = isA ? issue : issue - NA;
      const int c = ia*64 + lane;
      const int row = c>>3, slot = c&7;
      const int sg = slot ^ (row&7);
      const u16* base = isA ? (sg < 4 ? Ahi : Alo) : (sg < 4 ? Bhi : Blo);
      const int gr = (isA ? m0 : n0) + row;
      const u16* gp = base + (size_t)gr*K + k0 + (sg&3)*8;
      unsigned char* lp = (isA ? As : Bs) + ia*1024 + lane*16;
      gload16(gp, lp);
    }
    __syncthreads();
    bf16x8 ah[4], al[4], bh[NS], bl[NS];
    #pragma unroll
    for (int ms = 0; ms < 4; ++ms){
      const int r = wr*64 + ms*16 + li; const int x = (r&7)<<4;
      const unsigned char* p = As + r*128;
      ah[ms] = *(const bf16x8*)(p + ((g*16)^x));
      al[ms] = *(const bf16x8*)(p + ((64 + g*16)^x));
    }
    #pragma unroll
    for (int ns = 0; ns < NS; ++ns){
      const int r = wc*(BN/2) + ns*16 + li; const int x = (r&7)<<4;
      const unsigned char* p = Bs + r*128;
      bh[ns] = *(const bf16x8*)(p + ((g*16)^x));
      bl[ns] = *(const bf16x8*)(p + ((64 + g*16)^x));
    }
    #pragma unroll
    for (int ms = 0; ms < 4; ++ms)
      #pragma unroll
      for (int ns = 0; ns < NS; ++ns){
        acc[ms][ns] = __builtin_amdgcn_mfma_f32_16x16x32_bf16(ah[ms], bh[ns], acc[ms][ns], 0, 0, 0);
        acc[ms][ns] = __builtin_amdgcn_mfma_f32_16x16x32_bf16(ah[ms], bl[ns], acc[ms][ns], 0, 0, 0);
        acc[ms][ns] = __builtin_amdgcn_mfma_f32_16x16x32_bf16(al[ms], bh[ns], acc[ms][ns], 0, 0, 0);
      }
  }
  #pragma unroll
  for (int ms = 0; ms < 4; ++ms){
    #pragma unroll
    for (int ns = 0; ns < NS; ++ns){
      #pragma unroll
      for (int r = 0; r < 4; ++r){
        const int m = m0 + wr*64 + ms*16 + g*4 + r;
        const int n = n0 + wc*(BN/2) + ns*16 + li;
        float val = acc[ms][ns][r];
        if (FLAGS & GF_BIAS) val += bias[n];
        if (FLAGS & GF_RELU) val = fmaxf(val, 0.f);
        if (FLAGS & GF_QKV){
          u16 vh, vl; split2(val, vh, vl);
          if (n < 1024){
            const size_t ix = (size_t)m*1024 + n;
            Ohi[ix] = vh; Olo[ix] = vl;
          } else {
            const size_t ix = ((size_t)(m>>10)*DMOD + (n-1024))*TSEQ + (m&1023);
            Vhi[ix] = vh; Vlo[ix] = vl;
          }
        } else if (FLAGS & GF_SPLIT){
          u16 vh, vl; split2(val, vh, vl);
          const size_t ix = (size_t)m*N + n;
          Ohi[ix] = vh; Olo[ix] = vl;
        } else if (FLAGS & GF_PART){
          C[(size_t)blockIdx.y*M*N + (size_t)m*N + n] = val;
        } else {
          const size_t ix = (size_t)m*N + n;
          if (FLAGS & GF_ACC) val += C[ix];
          C[ix] = val;
        }
      }
    }
  }
}

// ---------------- ksum[b,t,h] = sum_a (k_hi + k_lo) from packed qk buffer ----
__global__ __launch_bounds__(256) void ksum_kernel(const u16* __restrict__ kh_,
    const u16* __restrict__ kl_, float* __restrict__ ks){
  int idx = blockIdx.x*256 + threadIdx.x;
  const size_t base = (size_t)(idx>>3)*1024 + 512 + (idx&7)*DHEAD;
  const u16* ph = kh_ + base;
  const u16* pl = kl_ + base;
  float s = 0.f;
  #pragma unroll
  for (int a = 0; a < DHEAD; a += 8){
    bf16x8 vh = *(const bf16x8*)(ph + a);
    bf16x8 vl = *(const bf16x8*)(pl + a);
    #pragma unroll
    for (int j = 0; j < 8; ++j) s += bf2f((u16)vh[j]) + bf2f((u16)vl[j]);
  }
  ks[idx] = s;
}

// ---- scatter event COUNTS once per launch: cnt[cell] = n0 | (n1<<8), u16/cell --
__global__ __launch_bounds__(256) void scatter_cnt(const int* __restrict__ ab,
    u32* __restrict__ cntw){
  int e = blockIdx.x*256 + threadIdx.x;
  int4 r = *reinterpret_cast<const int4*>(ab + (size_t)e*4);  // et, bi, ki, qi
  const size_t cell = ((size_t)r.y*TSEQ + r.z)*TSEQ + r.w;
  const u32 inc = (r.x ? 0x100u : 1u) << (16*(cell & 1));
  atomicAdd(cntw + (cell >> 1), inc);
}

// ---------------- per-tile attention compute (QK & PV full 3-pass) ------------
// bias decode: c = n0 + 256*n1 (exact in f32) -> bv = c*d0 + n1*(d1-256*d0).
__device__ __forceinline__ void tile_compute(
    const unsigned char* __restrict__ Klh, const unsigned char* __restrict__ Kll,
    const unsigned char* __restrict__ Vh, const unsigned char* __restrict__ Vl,
    unsigned char* __restrict__ Plh, unsigned char* __restrict__ Pll,
    const float* __restrict__ ksl, const u16* __restrict__ bb,
    float d0, float e1,
    int kt, int rowg0, int wid, int li, int g,
    const bf16x8* qah, const bf16x8* qal,
    f32x4* oacc, float* mrun, float* srun){
  f32x4 sacc[4] = {};
  #pragma unroll
  for (int jb = 0; jb < 4; ++jb){
    const int rb = (jb*16 + li)*128, x = (li & 7) << 4;
    #pragma unroll
    for (int k2 = 0; k2 < 2; ++k2){
      bf16x8 kfh = *(const bf16x8*)(Klh + rb + ((g*16 + k2*64)^x));
      bf16x8 kfl = *(const bf16x8*)(Kll + rb + ((g*16 + k2*64)^x));
      sacc[jb] = __builtin_amdgcn_mfma_f32_16x16x32_bf16(qah[k2], kfh, sacc[jb], 0, 0, 0);
      sacc[jb] = __builtin_amdgcn_mfma_f32_16x16x32_bf16(qah[k2], kfl, sacc[jb], 0, 0, 0);
      sacc[jb] = __builtin_amdgcn_mfma_f32_16x16x32_bf16(qal[k2], kfh, sacc[jb], 0, 0, 0);
    }
  }
  #pragma unroll
  for (int jb = 0; jb < 4; ++jb){
    const int colg = kt + jb*16 + li;
    const float ksv = ksl[jb*16 + li];
    #pragma unroll
    for (int r = 0; r < 4; ++r){
      const int rowg = rowg0 + r;
      const u32 c = bb[(size_t)rowg*TSEQ + colg];
      const float bv = fmaf((float)c, d0, (float)(c >> 8) * e1);
      float s = (sacc[jb][r] + bv * ksv) * ATT_SCALE;
      sacc[jb][r] = (colg <= rowg) ? s : -INFINITY;
    }
  }
  #pragma unroll
  for (int r = 0; r < 4; ++r){
    float tm = fmaxf(fmaxf(sacc[0][r], sacc[1][r]), fmaxf(sacc[2][r], sacc[3][r]));
    tm = fmaxf(tm, __shfl_xor(tm, 1));
    tm = fmaxf(tm, __shfl_xor(tm, 2));
    tm = fmaxf(tm, __shfl_xor(tm, 4));
    tm = fmaxf(tm, __shfl_xor(tm, 8));
    const float nm = fmaxf(mrun[r], tm);
    const float fac = __expf(mrun[r] - nm);
    mrun[r] = nm;
    float p0 = __expf(sacc[0][r] - nm);
    float p1 = __expf(sacc[1][r] - nm);
    float p2 = __expf(sacc[2][r] - nm);
    float p3 = __expf(sacc[3][r] - nm);
    float rs = p0 + p1 + p2 + p3;
    rs += __shfl_xor(rs, 1);
    rs += __shfl_xor(rs, 2);
    rs += __shfl_xor(rs, 4);
    rs += __shfl_xor(rs, 8);
    srun[r] = srun[r]*fac + rs;
    oacc[0][r] *= fac; oacc[1][r] *= fac; oacc[2][r] *= fac; oacc[3][r] *= fac;
    const int prow = g*4 + r;
    const int pb = wid*2048 + prow*128, px = (prow & 7) << 4;
    u16 ph0,pl0, ph1,pl1, ph2,pl2, ph3,pl3;
    split2(p0,ph0,pl0); split2(p1,ph1,pl1); split2(p2,ph2,pl2); split2(p3,ph3,pl3);
    *(u16*)(Plh + pb + ((li*2 +  0)^px)) = ph0;
    *(u16*)(Plh + pb + ((li*2 + 32)^px)) = ph1;
    *(u16*)(Plh + pb + ((li*2 + 64)^px)) = ph2;
    *(u16*)(Plh + pb + ((li*2 + 96)^px)) = ph3;
    *(u16*)(Pll + pb + ((li*2 +  0)^px)) = pl0;
    *(u16*)(Pll + pb + ((li*2 + 32)^px)) = pl1;
    *(u16*)(Pll + pb + ((li*2 + 64)^px)) = pl2;
    *(u16*)(Pll + pb + ((li*2 + 96)^px)) = pl3;
  }
  bf16x8 pah[2], pal[2];
  {
    const int pb = wid*2048 + li*128, x = (li & 7) << 4;
    pah[0] = *(const bf16x8*)(Plh + pb + ((g*16     )^x));
    pah[1] = *(const bf16x8*)(Plh + pb + ((g*16 + 64)^x));
    pal[0] = *(const bf16x8*)(Pll + pb + ((g*16     )^x));
    pal[1] = *(const bf16x8*)(Pll + pb + ((g*16 + 64)^x));
  }
  #pragma unroll
  for (int ja = 0; ja < 4; ++ja){
    const int vb = (ja*16 + li)*128, x = (li & 7) << 4;
    #pragma unroll
    for (int k2 = 0; k2 < 2; ++k2){
      bf16x8 vfh = *(const bf16x8*)(Vh + vb + ((g*16 + k2*64)^x));
      bf16x8 vfl = *(const bf16x8*)(Vl + vb + ((g*16 + k2*64)^x));
      oacc[ja] = __builtin_amdgcn_mfma_f32_16x16x32_bf16(pah[k2], vfh, oacc[ja], 0, 0, 0);
      oacc[ja] = __builtin_amdgcn_mfma_f32_16x16x32_bf16(pah[k2], vfl, oacc[ja], 0, 0, 0);
      oacc[ja] = __builtin_amdgcn_mfma_f32_16x16x32_bf16(pal[k2], vfh, oacc[ja], 0, 0, 0);
    }
  }
}

// ---------------- flash attention, causal-paired blocks (R13/R18 structure) ----
__global__ __launch_bounds__(256) void attn_split(
    const u16* __restrict__ qkh, const u16* __restrict__ qkl,
    const u16* __restrict__ vth, const u16* __restrict__ vtl,
    const float* __restrict__ ksum, const u16* __restrict__ cnt,
    const float* __restrict__ Ebl, const float* __restrict__ Esl,
    u16* __restrict__ ch_, u16* __restrict__ cl_){
  __shared__ __align__(16) unsigned char Klh[8192], Kll[8192], Vh[8192], Vl[8192];
  __shared__ __align__(16) unsigned char Plh[8192], Pll[8192];
  __shared__ float ksl[64];

  const int bid = blockIdx.x;                 // 256 = b(4) x p(8) x h(8)
  const int h = bid & 7, p = (bid >> 3) & 7, b = bid >> 6;
  const int qA0 = p*64, qB0 = (15-p)*64;
  const int tid = threadIdx.x, wid = tid >> 6, lane = tid & 63;
  const int li = lane & 15, g = lane >> 4;
  const int rowA0 = qA0 + wid*16 + g*4;
  const int rowB0 = qB0 + wid*16 + g*4;

  float d0 = 0.f, d1 = 0.f;
  #pragma unroll 8
  for (int a = 0; a < DHEAD; ++a){
    const float e = Esl[a];
    d0 += Ebl[a] * e;
    d1 += Ebl[DHEAD + a] * e;
  }
  const float e1 = d1 - 256.f*d0;

  bf16x8 qahA[2], qalA[2], qahB[2], qalB[2];
  {
    const size_t offA = (size_t)(b*TSEQ + qA0 + wid*16 + li)*1024 + h*DHEAD;
    const size_t offB = (size_t)(b*TSEQ + qB0 + wid*16 + li)*1024 + h*DHEAD;
    #pragma unroll
    for (int k2 = 0; k2 < 2; ++k2){
      qahA[k2] = *(const bf16x8*)(qkh + offA + g*8 + k2*32);
      qalA[k2] = *(const bf16x8*)(qkl + offA + g*8 + k2*32);
      qahB[k2] = *(const bf16x8*)(qkh + offB + g*8 + k2*32);
      qalB[k2] = *(const bf16x8*)(qkl + offB + g*8 + k2*32);
    }
  }

  f32x4 oaccA[4] = {}, oaccB[4] = {};
  float mrunA[4] = {-INFINITY,-INFINITY,-INFINITY,-INFINITY};
  float mrunB[4] = {-INFINITY,-INFINITY,-INFINITY,-INFINITY};
  float srunA[4] = {0.f,0.f,0.f,0.f};
  float srunB[4] = {0.f,0.f,0.f,0.f};

  const int krow = tid >> 2, part = tid & 3;
  const int lbase = krow*128, lx = (krow & 7) << 4;
  const u16* bb = cnt + (size_t)b*TSEQ*TSEQ;

  uint4 rk0, rk1, rk2, rk3, rv0, rv1, rv2, rv3;
  float ksr = 0.f;
  auto issue = [&](int kt){
    const size_t koff = (size_t)(b*TSEQ + kt + krow)*1024 + 512 + h*DHEAD + part*16;
    rk0 = *(const uint4*)(qkh + koff);
    rk1 = *(const uint4*)(qkh + koff + 8);
    rk2 = *(const uint4*)(qkl + koff);
    rk3 = *(const uint4*)(qkl + koff + 8);
    const size_t voff = ((size_t)b*DMOD + h*DHEAD + krow)*TSEQ + kt + part*16;
    rv0 = *(const uint4*)(vth + voff);
    rv1 = *(const uint4*)(vth + voff + 8);
    rv2 = *(const uint4*)(vtl + voff);
    rv3 = *(const uint4*)(vtl + voff + 8);
    if (tid < 64) ksr = ksum[(size_t)(b*TSEQ + kt + tid)*HNUM + h];
  };

  issue(0);
  for (int kt = 0; kt <= qB0; kt += 64){
    *(uint4*)(Klh + lbase + ((part*32     )^lx)) = rk0;
    *(uint4*)(Klh + lbase + ((part*32 + 16)^lx)) = rk1;
    *(uint4*)(Kll + lbase + ((part*32     )^lx)) = rk2;
    *(uint4*)(Kll + lbase + ((part*32 + 16)^lx)) = rk3;
    *(uint4*)(Vh  + lbase + ((part*32     )^lx)) = rv0;
    *(uint4*)(Vh  + lbase + ((part*32 + 16)^lx)) = rv1;
    *(uint4*)(Vl  + lbase + ((part*32     )^lx)) = rv2;
    *(uint4*)(Vl  + lbase + ((part*32 + 16)^lx)) = rv3;
    if (tid < 64) ksl[tid] = ksr;
    __syncthreads();
    if (kt + 64 <= qB0) issue(kt + 64);   // prefetch next tile under compute
    tile_compute(Klh, Kll, Vh, Vl, Plh, Pll, ksl, bb, d0, e1, kt, rowB0, wid, li, g,
                 qahB, qalB, oaccB, mrunB, srunB);
    if (kt <= qA0)
      tile_compute(Klh, Kll, Vh, Vl, Plh, Pll, ksl, bb, d0, e1, kt, rowA0, wid, li, g,
                   qahA, qalA, oaccA, mrunA, srunA);
    __syncthreads();
  }

  // ---- epilogue: normalize, split, store ctx for both tiles ----
  #pragma unroll
  for (int ja = 0; ja < 4; ++ja){
    #pragma unroll
    for (int r = 0; r < 4; ++r){
      {
        const float val = oaccB[ja][r] / srunB[r];
        u16 vh, vl; split2(val, vh, vl);
        const size_t ix = (size_t)(b*TSEQ + rowB0 + r)*DMOD + h*DHEAD + ja*16 + li;
        ch_[ix] = vh; cl_[ix] = vl;
      }
      {
        const float val = oaccA[ja][r] / srunA[r];
        u16 vh, vl; split2(val, vh, vl);
        const size_t ix = (size_t)(b*TSEQ + rowA0 + r)*DMOD + h*DHEAD + ja*16 + li;
        ch_[ix] = vh; cl_[ix] = vl;
      }
    }
  }
}

extern "C" void kernel_launch(void* const* d_in, const int* in_sizes, int n_in,
                              void* d_out, int out_size, void* d_ws, size_t ws_size,
                              hipStream_t stream){
  const float* states0 = (const float*)d_in[0];
  const int*   ab      = (const int*)d_in[2];
  const float* Wq = (const float*)d_in[3];
  const float* Wk = (const float*)d_in[4];
  const float* Wv = (const float*)d_in[5];
  const float* Wo = (const float*)d_in[6];
  const float* Eb = (const float*)d_in[7];
  const float* Es = (const float*)d_in[8];
  const float* ln1_s = (const float*)d_in[9];
  const float* ln1_b = (const float*)d_in[10];
  const float* ln2_s = (const float*)d_in[11];
  const float* ln2_b = (const float*)d_in[12];
  const float* lno_s = (const float*)d_in[13];
  const float* lno_b = (const float*)d_in[14];
  const float* W1 = (const float*)d_in[15];
  const float* b1 = (const float*)d_in[16];
  const float* W2 = (const float*)d_in[17];
  const float* b2 = (const float*)d_in[18];
  float* out = (float*)d_out;

  char* ws = (char*)d_ws;
  const size_t MB = 1024*1024;
  float* states = (float*)(ws);                       // 0-8 MB f32
  u16* xh  = (u16*)(ws + 8*MB);
  u16* xl  = (u16*)(ws + 12*MB);
  u16* qkh = (u16*)(ws + 16*MB);                      // q|k packed, stride 1024
  u16* qkl = (u16*)(ws + 24*MB);
  u16* vth = (u16*)(ws + 32*MB);                      // V transposed
  u16* vtl = (u16*)(ws + 36*MB);
  u16* cth = (u16*)(ws + 40*MB);
  u16* ctl = (u16*)(ws + 44*MB);
  float* ksum  = (float*)(ws + 48*MB);
  float* part  = (float*)(ws + 48*MB + 131072);       // 16 MB split-K partials
  char*  wA    = ws + 64*MB + 131072;                 // 4 MB wqkv+wo
  char*  wB    = wA + 4*MB;                           // 4 MB w1
  char*  wC    = wB + 4*MB;                           // 4 MB w2
  u16* hh = qkh;
  u16* hl = vth;
  u16* cnt = (u16*)d_out;                             // 8 MB packed counts

  u16* wqkvh = (u16*)(wA);
  u16* wqkvl = (u16*)(wA + 1536*1024);
  u16* woh   = (u16*)(wA + 3*MB);
  u16* wol   = (u16*)(wA + 3*MB + 512*1024);
  u16* w1h   = (u16*)(wB);
  u16* w1l   = (u16*)(wB + 2*MB);
  u16* w2h   = (u16*)(wC);
  u16* w2l   = (u16*)(wC + 2*MB);

  hipMemcpyAsync(states, states0, 8*MB, hipMemcpyDeviceToDevice, stream);
  hipMemsetAsync(d_out, 0, (size_t)BNUM*TSEQ*TSEQ*sizeof(u16), stream);
  scatter_cnt<<<NEVENTS/256, 256, 0, stream>>>(ab, (u32*)d_out);

  const int NROW = BNUM*TSEQ;
  dim3 blk(256);
  for (int l = 0; l < LNUM; ++l){
    wsplit6<<<768, blk, 0, stream>>>(Wq, Wk, Wv, Wo, W1, W2, l,
        wqkvh, wqkvl, woh, wol, w1h, w1l, w2h, w2l);

    // ln1: for l>0 fuses prev layer's W2 split-K reduce + b2[l-1] + residual
    ln_kernel<<<NROW, blk, 0, stream>>>(states,
        (l == 0) ? nullptr : part, (l == 0) ? nullptr : b2 + (size_t)(l-1)*DMOD,
        ln1_s + l*DMOD, ln1_b + l*DMOD, nullptr, xh, xl, 0);
    // QKV: BN=64 -> 768 blocks (3/CU)
    gemm_mfma<64,2, GF_SPLIT|GF_QKV><<<768, blk, 0, stream>>>(
        xh, xl, wqkvh, wqkvl, nullptr, nullptr, qkh, qkl, vth, vtl, NROW, 1536, DMOD, DMOD);
    ksum_kernel<<<(BNUM*TSEQ*HNUM)/256, blk, 0, stream>>>(qkh, qkl, ksum);
    attn_split<<<BNUM*HNUM*8, blk, 0, stream>>>(qkh, qkl, vth, vtl, ksum, cnt,
        Eb + (size_t)l*2*DHEAD, Es + (size_t)l*DHEAD, cth, ctl);
    gemm_mfma<64,2, GF_PART><<<dim3(256,2), blk, 0, stream>>>(
        cth, ctl, woh, wol, nullptr, part, nullptr, nullptr, nullptr, nullptr, NROW, DMOD, DMOD, DMOD/2);

    // ln2: fuses Wo split-K reduce + residual
    ln_kernel<<<NROW, blk, 0, stream>>>(states, part, nullptr,
        ln2_s + l*DMOD, ln2_b + l*DMOD, nullptr, xh, xl, 0);
    // W1: BN=64 -> 1024 blocks (4/CU)
    gemm_mfma<64,2, GF_BIAS|GF_RELU|GF_SPLIT><<<1024, blk, 0, stream>>>(
        xh, xl, w1h, w1l, b1 + (size_t)l*FDIM, nullptr, hh, hl, nullptr, nullptr, NROW, FDIM, DMOD, DMOD);
    gemm_mfma<64,2, GF_PART><<<dim3(256,2), blk, 0, stream>>>(
        hh, hl, w2h, w2l, nullptr, part, nullptr, nullptr, nullptr, nullptr, NROW, DMOD, FDIM, FDIM/2);
  }
  // final LN fuses layer-5 W2 reduce + b2[5] + residual (overwrites cnt scratch)
  ln_kernel<<<NROW, blk, 0, stream>>>(states, part, b2 + (size_t)(LNUM-1)*DMOD,
      lno_s, lno_b, out, nullptr, nullptr, 1);
}